// Round 15
// baseline (168.877 us; speedup 1.0000x reference)
//
#include <hip/hip_runtime.h>
#include <cmath>

#define LOG2E 1.4426950408889634f

typedef __attribute__((ext_vector_type(8))) __bf16 bf16x8;
typedef __attribute__((ext_vector_type(4))) float f32x4;
typedef __attribute__((ext_vector_type(16))) float f32x16;
typedef __attribute__((ext_vector_type(4))) float float4v;
typedef __attribute__((ext_vector_type(4))) unsigned int uint4v;
typedef __attribute__((ext_vector_type(8))) unsigned short ushort8v;
typedef __attribute__((ext_vector_type(2))) int int2v;

__device__ __forceinline__ unsigned short f2bf(float f) {
  unsigned int u = __builtin_bit_cast(unsigned int, f);
  u += 0x7fffu + ((u >> 16) & 1u);   // RNE
  return (unsigned short)(u >> 16);
}

__device__ __forceinline__ unsigned int cvtpk(float lo, float hi) {
  unsigned int r;
  asm volatile("v_cvt_pk_bf16_f32 %0, %1, %2" : "=v"(r) : "v"(lo), "v"(hi));
  return r;
}

// async global->LDS, 16B per lane; LDS dest = wave-uniform base + lane*16
__device__ __forceinline__ void gload_lds16(const unsigned short* g, unsigned short* l) {
  __builtin_amdgcn_global_load_lds(
      (const __attribute__((address_space(1))) unsigned int*)(const void*)g,
      (__attribute__((address_space(3))) unsigned int*)(void*)l, 16, 0, 0);
}

// ---------- kernel 1: Wt[w][n][k] = bf16(W_w[k][n] * scale), LDS tile transpose ----------
// grid (16, 3): 4x4 tiles of 64x64 per matrix. Coalesced read, coalesced write.
// Write side: 64 rows x 64 cols = 512 ushort8 chunks = 256 threads x 2 iters.
__global__ __launch_bounds__(256) void prep_w_kernel(
    const float* __restrict__ Wq, const float* __restrict__ Wk,
    const float* __restrict__ Wv, unsigned short* __restrict__ Wt) {
  __shared__ float lds[64 * 65];   // [n_local][k_local], pad 65

  const int w = blockIdx.y;
  const int kt = blockIdx.x & 3, nt = blockIdx.x >> 2;
  const float* W = (w == 0) ? Wq : ((w == 1) ? Wk : Wv);
  const float s = (w == 0) ? (LOG2E / 16.0f) : 1.0f;
  const int t = threadIdx.x;

#pragma unroll
  for (int it = 0; it < 4; ++it) {
    const int idx = it * 256 + t;
    const int r = idx >> 4, c4 = (idx & 15) * 4;          // k-row r, n-cols c4..c4+3
    const float4v v = *(const float4v*)(W + (size_t)(kt * 64 + r) * 256 + nt * 64 + c4);
#pragma unroll
    for (int j = 0; j < 4; ++j) lds[(c4 + j) * 65 + r] = v[j];
  }
  __syncthreads();
#pragma unroll
  for (int it = 0; it < 2; ++it) {                        // FIXED: 2 iters (was 4, OOB)
    const int idx = it * 256 + t;
    const int rn = idx >> 3, c8 = (idx & 7) * 8;          // n-row rn (0..63), k-cols c8..c8+7
    ushort8v o;
#pragma unroll
    for (int j = 0; j < 8; ++j) o[j] = f2bf(lds[rn * 65 + c8 + j] * s);
    *(ushort8v*)(Wt + w * 65536 + (size_t)(nt * 64 + rn) * 256 + kt * 64 + c8) = o;
  }
}

// ---------- kernel 2: fused q/k/v projection, coalesced V^T writeout (R13-proven) ----------
__global__ __launch_bounds__(256) void proj_kernel(
    const float* __restrict__ x, const unsigned short* __restrict__ Wt,
    const float* __restrict__ bq, const float* __restrict__ bk,
    const float* __restrict__ bv,
    unsigned short* __restrict__ q_o, unsigned short* __restrict__ k_o,
    unsigned short* __restrict__ vt_o) {
  __shared__ unsigned short vlds[128 * 72];   // 18KB, [d_local][s] pad 72

  const int mt = blockIdx.x;
  const int nfh = blockIdx.y;
  const int tid = threadIdx.x;
  const int wid = tid >> 6, lane = tid & 63, g = (lane >> 4) & 3, c = lane & 15;
  const int row_base = mt * 64 + wid * 16;

  bf16x8 a[8];
  const float* xr = x + (size_t)(row_base + c) * 256;
#pragma unroll
  for (int s = 0; s < 8; ++s) {
    const float4v v0 = *(const float4v*)(xr + s * 32 + g * 8);
    const float4v v1 = *(const float4v*)(xr + s * 32 + g * 8 + 4);
    union { bf16x8 v; unsigned short u[8]; } t;
#pragma unroll
    for (int j = 0; j < 4; ++j) { t.u[j] = f2bf(v0[j]); t.u[4 + j] = f2bf(v1[j]); }
    a[s] = t.v;
  }

  const unsigned short* w0 = Wt;
  const unsigned short* w1 = Wt + 65536;
  const unsigned short* w2 = Wt + 131072;

#pragma unroll
  for (int nfi = 0; nfi < 8; ++nfi) {
    const int nf = nfh * 8 + nfi;
    f32x4 aq = (f32x4){0.f, 0.f, 0.f, 0.f};
    f32x4 ak = (f32x4){0.f, 0.f, 0.f, 0.f};
    f32x4 av = (f32x4){0.f, 0.f, 0.f, 0.f};
    const unsigned short* r0 = w0 + (size_t)(nf * 16 + c) * 256;
    const unsigned short* r1 = w1 + (size_t)(nf * 16 + c) * 256;
    const unsigned short* r2 = w2 + (size_t)(nf * 16 + c) * 256;
#pragma unroll
    for (int s = 0; s < 8; ++s) {
      bf16x8 b0 = *(const bf16x8*)(r0 + s * 32 + g * 8);
      bf16x8 b1 = *(const bf16x8*)(r1 + s * 32 + g * 8);
      bf16x8 b2 = *(const bf16x8*)(r2 + s * 32 + g * 8);
      aq = __builtin_amdgcn_mfma_f32_16x16x32_bf16(a[s], b0, aq, 0, 0, 0);
      ak = __builtin_amdgcn_mfma_f32_16x16x32_bf16(a[s], b1, ak, 0, 0, 0);
      av = __builtin_amdgcn_mfma_f32_16x16x32_bf16(a[s], b2, av, 0, 0, 0);
    }
    const float bql = bq[nf * 16 + c] * (LOG2E / 16.0f);
    const float bkl = bk[nf * 16 + c];
    const float bvl = bv[nf * 16 + c];
#pragma unroll
    for (int r = 0; r < 4; ++r) {
      const int row = row_base + g * 4 + r;
      q_o[(size_t)row * 256 + nf * 16 + c] = f2bf(aq[r] + bql);
      k_o[(size_t)row * 256 + nf * 16 + c] = f2bf(ak[r] + bkl);
      vlds[(nfi * 16 + c) * 72 + (wid * 16 + g * 4 + r)] = f2bf(av[r] + bvl);
    }
  }

  __syncthreads();

  const int bb = mt >> 6;
  const int s0 = (mt & 63) * 64;
  unsigned short* vout = vt_o + ((size_t)bb * 256 + nfh * 128) * 4096 + s0;
#pragma unroll
  for (int it = 0; it < 4; ++it) {
    const int idx = it * 256 + tid;
    const int dl = idx >> 3, s8 = idx & 7;
    ushort8v val = *(const ushort8v*)(vlds + dl * 72 + s8 * 8);
    *(ushort8v*)(vout + (size_t)dl * 4096 + s8 * 8) = val;
  }
}

// ---------- kernel 3: causal flash attention, dual-group kv-split blocks ----------
// 512 blocks x 512 threads (8 waves), 1 block/CU (128KB LDS).
// Block = one 32-row q-tile; wave-groups g=0/1 sweep kv [0,S1) / [S1,T) with
// PRIVATE K/V buffers (no phases, no atomics). Every block runs S1<=32 steps;
// pairing qt <-> 127-qt across bid c <-> c+256 makes per-CU work uniform (~33).
// Waves (g, dh, wk): R13 step body verbatim; cross-(g,wk) l/O merge in-block
// via LDS (Klds reused as two 32KB oz buffers) with 3 epilogue barriers.
__global__ __launch_bounds__(512, 2) void attn_kernel(
    const unsigned short* __restrict__ qg, const unsigned short* __restrict__ kg,
    const unsigned short* __restrict__ vtg, float* __restrict__ out) {
  __shared__ unsigned short Klds[2][64 * 256];   // per-group, swizzled image (64KB)
  __shared__ unsigned short Vlds[2][256 * 64];   // per-group, swizzled image (64KB)
  __shared__ float llds[2][2][32];               // [g][wk][q]

  const int tid = threadIdx.x;
  const int wid = tid >> 6, lane = tid & 63;
  const int hi = lane >> 5, q5 = lane & 31;
  const int g = wid >> 2, dh = (wid >> 1) & 1, wk = wid & 1, wg = wid & 3;
  const int bid = blockIdx.x;
  const int half = bid >> 8, k6 = (bid >> 2) & 63, b = bid & 3;
  const int qt = half ? k6 : 127 - k6;           // pair qt <-> 127-qt on one CU
  const int T = (qt >> 1) + 1;
  const int S1 = (T + 1) >> 1;
  const int tb = g ? S1 : 0;
  const int te = g ? T : S1;

  const unsigned short* qb = qg + (size_t)b * 4096 * 256;
  const unsigned short* kb = kg + (size_t)b * 4096 * 256;
  const unsigned short* vb = vtg + (size_t)b * 256 * 4096;
  float* outb = out + (size_t)b * 4096 * 256;

  const int qrow = qt * 32 + q5;

  // Pre-swizzled global source offsets for global_load_lds (LDS dest linear).
  int koff[8], voff[8];
#pragma unroll
  for (int i = 0; i < 8; ++i) {
    const int kr = wg * 16 + i * 2 + (lane >> 5);
    const int c8 = (lane & 31) ^ (kr & 7);
    koff[i] = kr * 256 + c8 * 8;
    const int d = wg * 64 + i * 8 + (lane >> 3);
    const int c8v = (lane & 7) ^ (d & 7);
    voff[i] = d * 4096 + c8v * 8;
  }

  auto stage = [&](int t) {                      // group's 4 waves stage 64KB
    const unsigned short* kp = kb + (size_t)t * 16384;
    const unsigned short* vp = vb + t * 64;
#pragma unroll
    for (int i = 0; i < 8; ++i)
      gload_lds16(kp + koff[i], &Klds[g][(wg * 8 + i) * 512]);
#pragma unroll
    for (int i = 0; i < 8; ++i)
      gload_lds16(vp + voff[i], &Vlds[g][(wg * 8 + i) * 512]);
  };

  // Q B-fragments (16): lane: q-col = q5, kdim = s*16 + hi*8 + j
  bf16x8 bqf[16];
  {
    const unsigned short* qr = qb + (size_t)qrow * 256;
#pragma unroll
    for (int s = 0; s < 16; ++s) bqf[s] = *(const bf16x8*)(qr + s * 16 + hi * 8);
  }

  float l = 0.f;                     // per-lane partial row-sum (this g, wk strip)
  f32x16 o[4];                       // O^T partial for d-half dh
#pragma unroll
  for (int d = 0; d < 4; ++d)
#pragma unroll
    for (int r = 0; r < 16; ++r) o[d][r] = 0.f;

  const int krow = wk * 32 + q5;
  const int ksw = (krow & 7) << 3;
  const int kbase = krow * 256;

  int kcolr[16];
#pragma unroll
  for (int r = 0; r < 16; ++r) kcolr[r] = wk * 32 + (r & 3) + 8 * (r >> 2) + 4 * hi;

  if (tb < te) stage(tb);            // group-1 may be empty (T==1)

  for (int st = 0; st < S1; ++st) {
    const int t = tb + st;
    const bool act = t < te;
    __syncthreads();                 // (a) staged tile ready (drains vmcnt)

    if (act) {
      // ---- QK^T (swapped): S^T[k strip 32][q 32], 2 indep chains ----
      f32x16 sa, sb;
#pragma unroll
      for (int r = 0; r < 16; ++r) { sa[r] = 0.f; sb[r] = 0.f; }
#pragma unroll
      for (int s = 0; s < 8; ++s) {
        bf16x8 ka0 = *(const bf16x8*)(&Klds[g][(kbase + s * 16 + hi * 8) ^ ksw]);
        bf16x8 ka1 = *(const bf16x8*)(&Klds[g][(kbase + (s + 8) * 16 + hi * 8) ^ ksw]);
        sa = __builtin_amdgcn_mfma_f32_32x32x16_bf16(ka0, bqf[s], sa, 0, 0, 0);
        sb = __builtin_amdgcn_mfma_f32_32x32x16_bf16(ka1, bqf[s + 8], sb, 0, 0, 0);
      }
      f32x16 sc = sa + sb;

      // ---- causal mask: only the group owning kv tile T-1 hits it ----
      if (t == T - 1) {
#pragma unroll
        for (int r = 0; r < 16; ++r)
          if (t * 64 + kcolr[r] > qrow) sc[r] = -1e30f;
      }

      // ---- P = exp2(S) (zero-max), partial row-sum ----
      float p[16];
#pragma unroll
      for (int r = 0; r < 16; ++r) p[r] = __builtin_amdgcn_exp2f(sc[r]);
      {
        float s0 = (p[0] + p[1]) + (p[2] + p[3]);
        float s1 = (p[4] + p[5]) + (p[6] + p[7]);
        float s2 = (p[8] + p[9]) + (p[10] + p[11]);
        float s3 = (p[12] + p[13]) + (p[14] + p[15]);
        l += (s0 + s1) + (s2 + s3);
      }

      // ---- build P B-fragments in-register ----
      bf16x8 pfrag[2];
#pragma unroll
      for (int s2 = 0; s2 < 2; ++s2) {
        const int base = s2 * 8;
        unsigned int X = cvtpk(p[base + 0], p[base + 1]);
        unsigned int Y = cvtpk(p[base + 2], p[base + 3]);
        unsigned int Z = cvtpk(p[base + 4], p[base + 5]);
        unsigned int W = cvtpk(p[base + 6], p[base + 7]);
#if __has_builtin(__builtin_amdgcn_permlane32_swap)
        int2v rx = __builtin_amdgcn_permlane32_swap((int)X, (int)Z, false, false);
        int2v ry = __builtin_amdgcn_permlane32_swap((int)Y, (int)W, false, false);
        uint4v u = (uint4v){(unsigned)rx[0], (unsigned)ry[0], (unsigned)rx[1], (unsigned)ry[1]};
#else
        const unsigned int Xp = __shfl_xor((int)X, 32);
        const unsigned int Yp = __shfl_xor((int)Y, 32);
        const unsigned int Zp = __shfl_xor((int)Z, 32);
        const unsigned int Wp = __shfl_xor((int)W, 32);
        uint4v u = (uint4v){hi ? Zp : X, hi ? Wp : Y, hi ? Z : Xp, hi ? W : Yp};
#endif
        pfrag[s2] = __builtin_bit_cast(bf16x8, u);
      }

      // ---- PV (swapped): O^T[d-half dh][q 32] += V^T_strip . P ----
#pragma unroll
      for (int dblk = 0; dblk < 4; ++dblk) {
        const int drow = (dh * 4 + dblk) * 32 + q5;
        const int vsw = (drow & 7) << 3;
        const int vbase = drow * 64 + wk * 32;
#pragma unroll
        for (int s2 = 0; s2 < 2; ++s2) {
          bf16x8 va = *(const bf16x8*)(&Vlds[g][(vbase + s2 * 16 + hi * 8) ^ vsw]);
          o[dblk] = __builtin_amdgcn_mfma_f32_32x32x16_bf16(va, pfrag[s2], o[dblk], 0, 0, 0);
        }
      }
    }

    __syncthreads();                 // (b) all reads of tile t done
    if (t + 1 < te) stage(t + 1);    // drained by next (a)
  }

  // ---- epilogue: merge 4 partials (g x wk) in-block, normalized store ----
  l += __shfl_xor(l, 32);
  if (hi == 0 && dh == 0) llds[g][wk][q5] = l;
  __syncthreads();                   // no staging in flight (last stage cond false)
  const float L = llds[0][0][q5] + llds[0][1][q5] + llds[1][0][q5] + llds[1][1][q5];
  const float scale = 1.0f / L;

  float* oz0 = (float*)&Klds[0][0];  // 32KB: [256 d][32 q] f32 (group 0)
  float* oz1 = (float*)&Klds[1][0];  // 32KB: group 1
  float* ozg = g ? oz1 : oz0;

  if (wk == 1) {                     // pass 1: wk1 partials -> oz_g
#pragma unroll
    for (int dblk = 0; dblk < 4; ++dblk)
#pragma unroll
      for (int r = 0; r < 16; ++r) {
        const int dg = (dh * 4 + dblk) * 32 + (r & 3) + 8 * (r >> 2) + 4 * hi;
        ozg[dg * 32 + q5] = o[dblk][r];
      }
  }
  __syncthreads();
  if (wk == 0 && g == 1) {           // pass 2: oz1 <- g1 total (own + oz1)
#pragma unroll
    for (int dblk = 0; dblk < 4; ++dblk)
#pragma unroll
      for (int r = 0; r < 16; ++r) {
        const int dg = (dh * 4 + dblk) * 32 + (r & 3) + 8 * (r >> 2) + 4 * hi;
        oz1[dg * 32 + q5] += o[dblk][r];
      }
  }
  __syncthreads();
  if (wk == 0 && g == 0) {           // pass 3: own + oz0 + oz1, scale, store
#pragma unroll
    for (int dblk = 0; dblk < 4; ++dblk) {
#pragma unroll
      for (int q2 = 0; q2 < 4; ++q2) {
        float4v val;
#pragma unroll
        for (int e = 0; e < 4; ++e) {
          const int r = q2 * 4 + e;
          const int dg = (dh * 4 + dblk) * 32 + e + 8 * q2 + 4 * hi;
          val[e] = (o[dblk][r] + oz0[dg * 32 + q5] + oz1[dg * 32 + q5]) * scale;
        }
        *(float4v*)(outb + (size_t)qrow * 256 + (dh * 4 + dblk) * 32 + 8 * q2 + 4 * hi) = val;
      }
    }
  }
}

extern "C" void kernel_launch(void* const* d_in, const int* in_sizes, int n_in,
                              void* d_out, int out_size, void* d_ws, size_t ws_size,
                              hipStream_t stream) {
  (void)in_sizes; (void)n_in; (void)out_size; (void)ws_size;
  const float* x  = (const float*)d_in[0];
  const float* Wq = (const float*)d_in[1];
  const float* bq = (const float*)d_in[2];
  const float* Wk = (const float*)d_in[3];
  const float* bk = (const float*)d_in[4];
  const float* Wv = (const float*)d_in[5];
  const float* bv = (const float*)d_in[6];
  float* out = (float*)d_out;

  unsigned short* qs  = (unsigned short*)d_ws;                 // [4][4096][256] bf16
  unsigned short* ks  = qs  + (size_t)16384 * 256;             // [4][4096][256] bf16
  unsigned short* vts = ks  + (size_t)16384 * 256;             // [4][256][4096] bf16 (V^T)
  unsigned short* Wt  = vts + (size_t)16384 * 256;             // [3][256][256]  bf16 (W^T)

  prep_w_kernel<<<dim3(16, 3), 256, 0, stream>>>(Wq, Wk, Wv, Wt);
  proj_kernel<<<dim3(256, 2), 256, 0, stream>>>(x, Wt, bq, bk, bv, qs, ks, vts);
  attn_kernel<<<512, 512, 0, stream>>>(qs, ks, vts, out);
}